// Round 24
// baseline (250.287 us; speedup 1.0000x reference)
//
#include <hip/hip_runtime.h>
#include <math.h>

#define NTA 50000
#define NN 1600000
#define NMAX 16
#define NO 4
#define HID 128
#define SLOTS 80        // padded per-atom capacity; counts ~Binom(1.6M,1/50e3): mean 32, sigma 5.7
#define NB1 1024        // phase-1 blocks
#define PPB 1563        // pairs per phase-1 block (1024*1563 >= NN)
#define MAXPPT 7        // ceil(PPB/256) pairs per thread
#define NBKT 196        // coarse buckets of 256 atoms (t>>8); 196*256 = 50176 >= NTA
#define SCAN_N (NBKT * NB1)   // 200704 histogram cells
#define SCAN_NBLK 196         // 200704 / 1024 exactly

static constexpr float PI_OVER_RCUT = 3.14159265358979323846f / 6.0f;

// blob record: (x, y, z, jw) ; jw bits 0-15 jidx, 16-17 jsym, 18-25 tl (= t & 255)
// rec4 record (packed by k_p2): {x:f16|y:f16, z:f16|unused, fi:int (blob index), jw}
// Ftab[fi*4+ng] : ushort4 of f16 fcut*radial for channels 4ng..4ng+3 (iteration-invariant)

__device__ __forceinline__ unsigned f2h(float f) {
    _Float16 h = (_Float16)f;
    return (unsigned)*(unsigned short*)&h;
}
__device__ __forceinline__ float h2f(unsigned u) {
    unsigned short s = (unsigned short)u;
    _Float16 h;
    *(unsigned short*)&h = s;
    return (float)h;
}

// ---------- phase 1a: per-(bucket,block) histogram ----------
__global__ __launch_bounds__(256) void k_p1_count(const int* __restrict__ iidx,
                                                  int* __restrict__ cnt1) {
    __shared__ int h[NBKT];
    int blk = blockIdx.x;
    if (threadIdx.x < NBKT) h[threadIdx.x] = 0;
    __syncthreads();
    int pend = min(NN, (blk + 1) * PPB);
    for (int p = blk * PPB + threadIdx.x; p < pend; p += 256)
        atomicAdd(&h[iidx[p] >> 8], 1);
    __syncthreads();
    if (threadIdx.x < NBKT) cnt1[threadIdx.x * NB1 + blk] = h[threadIdx.x];
}

// ---------- exclusive scan over cnt1 (bucket-major) ----------
__global__ void k_scan1(const int* __restrict__ counts, int* __restrict__ offsets,
                        int* __restrict__ blksum) {
    __shared__ int lds[1024];
    int i = blockIdx.x * 1024 + threadIdx.x;
    int v = counts[i];  // SCAN_N is an exact multiple of 1024
    lds[threadIdx.x] = v;
    __syncthreads();
    int sum = v;
    for (int off = 1; off < 1024; off <<= 1) {
        int t = (threadIdx.x >= off) ? lds[threadIdx.x - off] : 0;
        __syncthreads();
        sum += t;
        lds[threadIdx.x] = sum;
        __syncthreads();
    }
    offsets[i] = sum - v;
    if (threadIdx.x == 1023) blksum[blockIdx.x] = sum;
}

__global__ void k_scan2(int* __restrict__ blksum) {
    if (threadIdx.x == 0) {
        int acc = 0;
        for (int b = 0; b < SCAN_NBLK; ++b) {
            int v = blksum[b];
            blksum[b] = acc;
            acc += v;
        }
    }
}

__global__ void k_scan3(int* __restrict__ offsets, const int* __restrict__ blksum) {
    int i = blockIdx.x * 1024 + threadIdx.x;
    offsets[i] += blksum[blockIdx.x];
}

// ---------- phase 1b: in-LDS counting sort, then dense burst write-out ----------
__global__ __launch_bounds__(256) void k_p1_sort(
    const float* __restrict__ disp, const int* __restrict__ iidx,
    const int* __restrict__ jidx, const int* __restrict__ jsym,
    const int* __restrict__ off, float4* __restrict__ blob) {
    __shared__ int h[256];        // hist -> exclusive scan (padded to 256)
    __shared__ int goff[NBKT];    // global segment offset for (bucket, this block)
    __shared__ float4 buf[PPB];   // bucket-sorted records
    __shared__ int gaddr[PPB];    // per-record global index
    int blk = blockIdx.x;
    int tid = threadIdx.x;
    h[tid] = 0;
    if (tid < NBKT) goff[tid] = off[tid * NB1 + blk];
    __syncthreads();
    int base = blk * PPB;
    int pend = min(NN, base + PPB);

    int myb[MAXPPT], myr[MAXPPT];
#pragma unroll
    for (int i = 0; i < MAXPPT; ++i) {
        int p = base + i * 256 + tid;
        myb[i] = -1;
        if (p < pend) {
            int b = iidx[p] >> 8;
            myb[i] = b;
            myr[i] = atomicAdd(&h[b], 1);
        }
    }
    __syncthreads();
    int cnt_t = h[tid];  // own count (pre-scan)
    // inclusive Hillis-Steele scan over 256 entries
    for (int s = 1; s < 256; s <<= 1) {
        int val = (tid >= s) ? h[tid - s] : 0;
        __syncthreads();
        h[tid] += val;
        __syncthreads();
    }
    h[tid] -= cnt_t;  // -> exclusive
    __syncthreads();

#pragma unroll
    for (int i = 0; i < MAXPPT; ++i) {
        if (myb[i] >= 0) {
            int p = base + i * 256 + tid;
            int b = myb[i];
            int lpos = h[b] + myr[i];
            int tl = iidx[p] & 255;
            int jw = jidx[p] | (jsym[p] << 16) | (tl << 18);
            buf[lpos] = make_float4(disp[3 * p + 0], disp[3 * p + 1], disp[3 * p + 2],
                                    __int_as_float(jw));
            gaddr[lpos] = goff[b] + myr[i];
        }
    }
    __syncthreads();
    int total = pend - base;
    for (int i = tid; i < total; i += 256)
        blob[gaddr[i]] = buf[i];
}

// ---------- phase 2: CSR placement + ONE-TIME radial table (iteration-invariant) + Csn fill ----------
__global__ __launch_bounds__(512) void k_p2(
    const float4* __restrict__ blob, const int* __restrict__ off,
    const float* __restrict__ alpha, const float* __restrict__ rs,
    const float* __restrict__ sp, const int* __restrict__ symbols,
    float4* __restrict__ rec4, int* __restrict__ counts,
    ushort4* __restrict__ Ftab, float* __restrict__ Csn) {
    __shared__ int cur[256];
    __shared__ float2 alrv[4][16];
    int b = blockIdx.x;
    if (threadIdx.x < 256) cur[threadIdx.x] = 0;
    if (threadIdx.x < 64) {
        int js = threadIdx.x >> 4, n = threadIdx.x & 15;
        alrv[js][n] = make_float2(alpha[js * NMAX + n], rs[js * NMAX + n]);
    }
    __syncthreads();
    int start = off[b * NB1];
    int end = (b == NBKT - 1) ? NN : off[(b + 1) * NB1];
    for (int i = start + threadIdx.x; i < end; i += 512) {
        float4 r = blob[i];
        int jw = __float_as_int(r.w);
        int tl = ((unsigned)jw >> 18) & 255;
        int js = (jw >> 16) & 3;
        float dd = sqrtf(r.x * r.x + r.y * r.y + r.z * r.z);
        float cc = __cosf(dd * PI_OVER_RCUT) + 1.0f;
        float fcut = 0.25f * cc * cc;
        // 16 radials, f16-packed, coalesced write (dense blob order)
#pragma unroll
        for (int g = 0; g < 4; ++g) {
            float2 a0 = alrv[js][4 * g + 0], a1 = alrv[js][4 * g + 1];
            float2 a2 = alrv[js][4 * g + 2], a3 = alrv[js][4 * g + 3];
            float e0 = dd - a0.y, e1 = dd - a1.y, e2 = dd - a2.y, e3 = dd - a3.y;
            ushort4 fv;
            fv.x = (unsigned short)f2h(fcut * __expf(a0.x * e0 * e0));
            fv.y = (unsigned short)f2h(fcut * __expf(a1.x * e1 * e1));
            fv.z = (unsigned short)f2h(fcut * __expf(a2.x * e2 * e2));
            fv.w = (unsigned short)f2h(fcut * __expf(a3.x * e3 * e3));
            Ftab[(size_t)i * 4 + g] = fv;
        }
        float4 o;
        o.x = __uint_as_float(f2h(r.x) | (f2h(r.y) << 16));
        o.y = __uint_as_float(f2h(r.z));
        o.z = __int_as_float(i);   // blob index -> Ftab row
        o.w = r.w;
        int pos = atomicAdd(&cur[tl], 1);
        if (pos < SLOTS) rec4[(size_t)(b * 256 + tl) * SLOTS + pos] = o;
    }
    __syncthreads();
    if (threadIdx.x < 256) {
        int t = b * 256 + threadIdx.x;
        if (t < NTA) counts[t] = cur[threadIdx.x];
    }
    // Csn init for this bucket (replaces k_csn)
    for (int i = threadIdx.x; i < 256 * NMAX; i += 512) {
        int tl = i >> 4;
        int t = b * 256 + tl;
        if (t < NTA) Csn[(size_t)t * NMAX + (i & 15)] = sp[symbols[t] * NMAX + (i & 15)];
    }
}

// ---------------- density: FOUR atoms per wave; radial from Ftab (no transcendentals) ----------------
// lane = a*16 + p*4 + ng. Linear atom order (aperm regressed, r23).
__global__ __launch_bounds__(256) void k_density(
    const float4* __restrict__ rec4, const int* __restrict__ counts,
    const ushort4* __restrict__ Ftab,
    const float* __restrict__ Csn, const float* __restrict__ orb,  // [2][16][4] slice
    float* __restrict__ rho_out) {
    int wave = threadIdx.x >> 6;
    int lane = threadIdx.x & 63;
    int a = lane >> 4;        // 0..3 atom-in-wave
    int p = (lane >> 2) & 3;  // 0..3 pair slot
    int ng = lane & 3;        // 0..3 channel group
    int c0 = 4 * ng;
    int t = blockIdx.x * 16 + wave * 4 + a;
    int cnt = counts[t];
    if (cnt > SLOTS) cnt = SLOTS;
    int maxc = max(cnt, __shfl_xor(cnt, 16));
    maxc = max(maxc, __shfl_xor(maxc, 32));
    const float4* rbase = rec4 + (size_t)t * SLOTS;

    float acc[16];
#pragma unroll
    for (int i = 0; i < 16; ++i) acc[i] = 0.f;

#pragma unroll 2
    for (int kk = 0; kk < maxc; kk += 4) {
        int k = kk + p;
        bool m = (k < cnt);
        float4 R = rbase[m ? k : 0];
        int jw = __float_as_int(R.w);
        int jj = m ? (jw & 0xFFFF) : 0;
        int fi = m ? __float_as_int(R.z) : 0;  // fi is an ADDRESS: must scrub poison
        unsigned w0 = __float_as_uint(R.x);
        unsigned w1 = __float_as_uint(R.y);
        float x = h2f(w0 & 0xFFFFu);
        float y = h2f(w0 >> 16);
        float z = h2f(w1 & 0xFFFFu);
        ushort4 Fv = Ftab[(size_t)fi * 4 + ng];
        float4 C4 = *(const float4*)&Csn[jj * NMAX + c0];
        float f0 = h2f(Fv.x), f1 = h2f(Fv.y), f2 = h2f(Fv.z), f3 = h2f(Fv.w);
        if (!m) { f0 = 0.f; f1 = 0.f; f2 = 0.f; f3 = 0.f; }
        float fc0 = f0 * C4.x, fc1 = f1 * C4.y, fc2 = f2 * C4.z, fc3 = f3 * C4.w;
        acc[0] += fc0; acc[1] += fc1; acc[2] += fc2; acc[3] += fc3;
        acc[4] += fc0 * x; acc[5] += fc1 * x; acc[6] += fc2 * x; acc[7] += fc3 * x;
        acc[8] += fc0 * y; acc[9] += fc1 * y; acc[10] += fc2 * y; acc[11] += fc3 * y;
        acc[12] += fc0 * z; acc[13] += fc1 * z; acc[14] += fc2 * z; acc[15] += fc3 * z;
    }

#pragma unroll
    for (int i = 0; i < 16; ++i) {
        acc[i] += __shfl_xor(acc[i], 4);
        acc[i] += __shfl_xor(acc[i], 8);
    }

    float pt[16];
#pragma unroll
    for (int l = 0; l < 4; ++l) {
        const float* Wrow = orb + ((l > 0) ? 1 : 0) * (NMAX * NO);
#pragma unroll
        for (int o = 0; o < 4; ++o) {
            float s = 0.f;
#pragma unroll
            for (int c = 0; c < 4; ++c)
                s += Wrow[(c0 + c) * NO + o] * acc[l * 4 + c];
            pt[l * 4 + o] = s;
        }
    }
#pragma unroll
    for (int i = 0; i < 16; ++i) {
        pt[i] += __shfl_xor(pt[i], 1);
        pt[i] += __shfl_xor(pt[i], 2);
    }
    float r0 = 0.f, r1 = 0.f, r2 = 0.f, r3 = 0.f;
#pragma unroll
    for (int l = 0; l < 4; ++l) {
        r0 += pt[l * 4 + 0] * pt[l * 4 + 0];
        r1 += pt[l * 4 + 1] * pt[l * 4 + 1];
        r2 += pt[l * 4 + 2] * pt[l * 4 + 2];
        r3 += pt[l * 4 + 3] * pt[l * 4 + 3];
    }
    if (p == 0) {
        float v = (ng == 0) ? r0 : (ng == 1) ? r1 : (ng == 2) ? r2 : r3;
        rho_out[t * NO + ng] = v;
    }
}

// ---------------- MLP: one wave per atom, Csn += g ----------------
__global__ __launch_bounds__(256) void k_mlp(
    const float* __restrict__ rho, const int* __restrict__ symbols,
    const float* __restrict__ W1, const float* __restrict__ b1,
    const float* __restrict__ W2, const float* __restrict__ b2,
    float* __restrict__ Csn) {
    __shared__ float h_lds[4][HID];
    int wave = threadIdx.x >> 6;
    int lane = threadIdx.x & 63;
    int t = blockIdx.x * 4 + wave;
    int sym = symbols[t];
    float r0 = rho[t * 4 + 0];
    float r1 = rho[t * 4 + 1];
    float r2 = rho[t * 4 + 2];
    float r3 = rho[t * 4 + 3];
    const float* w1 = W1 + sym * NO * HID;
    const float* bb1 = b1 + sym * HID;
#pragma unroll
    for (int s = 0; s < 2; ++s) {
        int j = lane + s * 64;
        float hv = bb1[j] + r0 * w1[0 * HID + j] + r1 * w1[1 * HID + j] +
                   r2 * w1[2 * HID + j] + r3 * w1[3 * HID + j];
        hv = (hv >= 0.f) ? hv : 0.01f * hv;
        h_lds[wave][j] = hv;
    }
    __syncthreads();
    int n = lane & 15, q = lane >> 4;
    const float* w2 = W2 + sym * HID * NMAX;
    float g = 0.f;
#pragma unroll 8
    for (int k = 0; k < 32; ++k) {
        int j = q * 32 + k;
        g += h_lds[wave][j] * w2[j * NMAX + n];
    }
    g += __shfl_xor(g, 16);
    g += __shfl_xor(g, 32);
    if (lane < 16) {
        Csn[t * NMAX + n] += g + b2[sym * NMAX + n];
    }
}

extern "C" void kernel_launch(void* const* d_in, const int* in_sizes, int n_in,
                              void* d_out, int out_size, void* d_ws, size_t ws_size,
                              hipStream_t stream) {
    const float* disp    = (const float*)d_in[0];
    // d_in[1] (dist) not read — recomputed from disp in k_p2
    const float* alpha   = (const float*)d_in[2];
    const float* rs      = (const float*)d_in[3];
    const float* sp      = (const float*)d_in[4];
    const float* orb     = (const float*)d_in[5];  // (3, 2, 16, 4)
    const float* W1      = (const float*)d_in[6];
    const float* b1      = (const float*)d_in[7];
    const float* W2      = (const float*)d_in[8];
    const float* b2      = (const float*)d_in[9];
    const int* symbols   = (const int*)d_in[10];
    const int* iidx      = (const int*)d_in[11];
    const int* jidx      = (const int*)d_in[12];
    const int* jsym      = (const int*)d_in[13];

    char* base = (char*)d_ws;
    size_t off_b = 0;
    int* cnt1    = (int*)(base + off_b); off_b += (size_t)SCAN_N * 4;   // 803 KB
    int* offs    = (int*)(base + off_b); off_b += (size_t)SCAN_N * 4;   // 803 KB
    int* blksum  = (int*)(base + off_b); off_b += 1024;
    int* counts  = (int*)(base + off_b); off_b += (size_t)NTA * 4;      // 200 KB
    off_b = (off_b + 15) & ~(size_t)15;
    float4* blob = (float4*)(base + off_b); off_b += (size_t)NN * 16;   // 25.6 MB
    off_b = (off_b + 15) & ~(size_t)15;
    float4* rec4 = (float4*)(base + off_b); off_b += (size_t)NTA * SLOTS * 16;  // 64 MB
    off_b = (off_b + 15) & ~(size_t)15;
    ushort4* Ftab = (ushort4*)(base + off_b); off_b += (size_t)NN * 4 * 8;      // 51.2 MB
    float* Csn   = (float*)(base + off_b);  off_b += (size_t)NTA * NMAX * 4;    // 3.2 MB
    float* rho   = (float*)(base + off_b);  off_b += (size_t)NTA * NO * 4;      // 0.8 MB
    // total ~147 MB

    k_p1_count<<<NB1, 256, 0, stream>>>(iidx, cnt1);
    k_scan1<<<SCAN_NBLK, 1024, 0, stream>>>(cnt1, offs, blksum);
    k_scan2<<<1, 64, 0, stream>>>(blksum);
    k_scan3<<<SCAN_NBLK, 1024, 0, stream>>>(offs, blksum);
    k_p1_sort<<<NB1, 256, 0, stream>>>(disp, iidx, jidx, jsym, offs, blob);
    k_p2<<<NBKT, 512, 0, stream>>>(blob, offs, alpha, rs, sp, symbols,
                                   rec4, counts, Ftab, Csn);

    const int ORB_SLICE = 2 * NMAX * NO;  // 128 floats per loop-iteration slice
    k_density<<<NTA / 16, 256, 0, stream>>>(rec4, counts, Ftab, Csn,
                                            orb + 0 * ORB_SLICE, rho);
    k_mlp<<<NTA / 4, 256, 0, stream>>>(rho, symbols, W1, b1, W2, b2, Csn);
    k_density<<<NTA / 16, 256, 0, stream>>>(rec4, counts, Ftab, Csn,
                                            orb + 1 * ORB_SLICE, rho);
    k_mlp<<<NTA / 4, 256, 0, stream>>>(rho, symbols, W1, b1, W2, b2, Csn);
    k_density<<<NTA / 16, 256, 0, stream>>>(rec4, counts, Ftab, Csn,
                                            orb + 2 * ORB_SLICE, (float*)d_out);
}

// Round 25
// 171.182 us; speedup vs baseline: 1.4621x; 1.4621x over previous
//
#include <hip/hip_runtime.h>
#include <math.h>

#define NTA 50000
#define NN 1600000
#define NMAX 16
#define NO 4
#define HID 128
#define SLOTS 80        // padded per-atom capacity; counts ~Binom(1.6M,1/50e3): mean 32, sigma 5.7
#define NB1 1024        // phase-1 blocks
#define PPB 1563        // pairs per phase-1 block (1024*1563 >= NN)
#define MAXPPT 7        // ceil(PPB/256) pairs per thread
#define NBKT 196        // coarse buckets of 256 atoms (t>>8); 196*256 = 50176 >= NTA
#define SCAN_N (NBKT * NB1)   // 200704 histogram cells
#define SCAN_NBLK 196         // 200704 / 1024 exactly

static constexpr float PI_OVER_RCUT = 3.14159265358979323846f / 6.0f;

// blob record: (x, y, z, jw) ; jw bits 0-15 jidx, 16-17 jsym, 18-25 tl (= t & 255)
// rec4 record (packed by k_p2): {x:f16|y:f16, z:f16|fcut:u16fix, dd:f32, jw}

__device__ __forceinline__ unsigned f2h(float f) {
    _Float16 h = (_Float16)f;
    return (unsigned)*(unsigned short*)&h;
}
__device__ __forceinline__ float h2f(unsigned u) {
    unsigned short s = (unsigned short)u;
    _Float16 h;
    *(unsigned short*)&h = s;
    return (float)h;
}

// ---------- phase 1a: per-(bucket,block) histogram ----------
__global__ __launch_bounds__(256) void k_p1_count(const int* __restrict__ iidx,
                                                  int* __restrict__ cnt1) {
    __shared__ int h[NBKT];
    int blk = blockIdx.x;
    if (threadIdx.x < NBKT) h[threadIdx.x] = 0;
    __syncthreads();
    int pend = min(NN, (blk + 1) * PPB);
    for (int p = blk * PPB + threadIdx.x; p < pend; p += 256)
        atomicAdd(&h[iidx[p] >> 8], 1);
    __syncthreads();
    if (threadIdx.x < NBKT) cnt1[threadIdx.x * NB1 + blk] = h[threadIdx.x];
}

// ---------- exclusive scan over cnt1 (bucket-major) ----------
__global__ void k_scan1(const int* __restrict__ counts, int* __restrict__ offsets,
                        int* __restrict__ blksum) {
    __shared__ int lds[1024];
    int i = blockIdx.x * 1024 + threadIdx.x;
    int v = counts[i];  // SCAN_N is an exact multiple of 1024
    lds[threadIdx.x] = v;
    __syncthreads();
    int sum = v;
    for (int off = 1; off < 1024; off <<= 1) {
        int t = (threadIdx.x >= off) ? lds[threadIdx.x - off] : 0;
        __syncthreads();
        sum += t;
        lds[threadIdx.x] = sum;
        __syncthreads();
    }
    offsets[i] = sum - v;
    if (threadIdx.x == 1023) blksum[blockIdx.x] = sum;
}

__global__ void k_scan2(int* __restrict__ blksum) {
    if (threadIdx.x == 0) {
        int acc = 0;
        for (int b = 0; b < SCAN_NBLK; ++b) {
            int v = blksum[b];
            blksum[b] = acc;
            acc += v;
        }
    }
}

__global__ void k_scan3(int* __restrict__ offsets, const int* __restrict__ blksum) {
    int i = blockIdx.x * 1024 + threadIdx.x;
    offsets[i] += blksum[blockIdx.x];
}

// ---------- phase 1b: in-LDS counting sort, then dense burst write-out ----------
__global__ __launch_bounds__(256) void k_p1_sort(
    const float* __restrict__ disp, const int* __restrict__ iidx,
    const int* __restrict__ jidx, const int* __restrict__ jsym,
    const int* __restrict__ off, float4* __restrict__ blob) {
    __shared__ int h[256];        // hist -> exclusive scan (padded to 256)
    __shared__ int goff[NBKT];    // global segment offset for (bucket, this block)
    __shared__ float4 buf[PPB];   // bucket-sorted records
    __shared__ int gaddr[PPB];    // per-record global index
    int blk = blockIdx.x;
    int tid = threadIdx.x;
    h[tid] = 0;
    if (tid < NBKT) goff[tid] = off[tid * NB1 + blk];
    __syncthreads();
    int base = blk * PPB;
    int pend = min(NN, base + PPB);

    int myb[MAXPPT], myr[MAXPPT];
#pragma unroll
    for (int i = 0; i < MAXPPT; ++i) {
        int p = base + i * 256 + tid;
        myb[i] = -1;
        if (p < pend) {
            int b = iidx[p] >> 8;
            myb[i] = b;
            myr[i] = atomicAdd(&h[b], 1);
        }
    }
    __syncthreads();
    int cnt_t = h[tid];  // own count (pre-scan)
    // inclusive Hillis-Steele scan over 256 entries
    for (int s = 1; s < 256; s <<= 1) {
        int val = (tid >= s) ? h[tid - s] : 0;
        __syncthreads();
        h[tid] += val;
        __syncthreads();
    }
    h[tid] -= cnt_t;  // -> exclusive
    __syncthreads();

#pragma unroll
    for (int i = 0; i < MAXPPT; ++i) {
        if (myb[i] >= 0) {
            int p = base + i * 256 + tid;
            int b = myb[i];
            int lpos = h[b] + myr[i];
            int tl = iidx[p] & 255;
            int jw = jidx[p] | (jsym[p] << 16) | (tl << 18);
            buf[lpos] = make_float4(disp[3 * p + 0], disp[3 * p + 1], disp[3 * p + 2],
                                    __int_as_float(jw));
            gaddr[lpos] = goff[b] + myr[i];
        }
    }
    __syncthreads();
    int total = pend - base;
    for (int i = tid; i < total; i += 256)
        blob[gaddr[i]] = buf[i];
}

// ---------- phase 2: padded-CSR placement + dd/fcut precompute + Csn fill ----------
__global__ __launch_bounds__(512) void k_p2(
    const float4* __restrict__ blob, const int* __restrict__ off,
    const float* __restrict__ sp, const int* __restrict__ symbols,
    float4* __restrict__ rec4, int* __restrict__ counts,
    float* __restrict__ Csn) {
    __shared__ int cur[256];
    int b = blockIdx.x;
    if (threadIdx.x < 256) cur[threadIdx.x] = 0;
    __syncthreads();
    int start = off[b * NB1];
    int end = (b == NBKT - 1) ? NN : off[(b + 1) * NB1];
    for (int i = start + threadIdx.x; i < end; i += 512) {
        float4 r = blob[i];
        int jw = __float_as_int(r.w);
        int tl = ((unsigned)jw >> 18) & 255;
        float dd = sqrtf(r.x * r.x + r.y * r.y + r.z * r.z);
        float cc = __cosf(dd * PI_OVER_RCUT) + 1.0f;
        float fcut = 0.25f * cc * cc;
        unsigned fq = (unsigned)(fcut * 65535.0f + 0.5f);
        if (fq > 65535u) fq = 65535u;
        float4 o;
        o.x = __uint_as_float(f2h(r.x) | (f2h(r.y) << 16));
        o.y = __uint_as_float(f2h(r.z) | (fq << 16));
        o.z = dd;
        o.w = r.w;
        int pos = atomicAdd(&cur[tl], 1);
        if (pos < SLOTS) rec4[(size_t)(b * 256 + tl) * SLOTS + pos] = o;
    }
    __syncthreads();
    if (threadIdx.x < 256) {
        int t = b * 256 + threadIdx.x;
        if (t < NTA) counts[t] = cur[threadIdx.x];
    }
    // Csn init for this bucket (replaces the k_csn launch)
    for (int i = threadIdx.x; i < 256 * NMAX; i += 512) {
        int tl = i >> 4;
        int t = b * 256 + tl;
        if (t < NTA) Csn[(size_t)t * NMAX + (i & 15)] = sp[symbols[t] * NMAX + (i & 15)];
    }
}

// ---------------- density: FOUR atoms per wave; dd/fcut from record; alrv in LDS ----------------
// lane = a*16 + p*4 + ng.  (r20 keeper version — proven 169.7 us config)
__global__ __launch_bounds__(256) void k_density(
    const float4* __restrict__ rec4, const int* __restrict__ counts,
    const float* __restrict__ alpha, const float* __restrict__ rs,
    const float* __restrict__ Csn, const float* __restrict__ orb,  // [2][16][4] slice
    float* __restrict__ rho_out) {
    __shared__ float2 alrv[4][16];   // (alpha, rs) per species x channel
    if (threadIdx.x < 64) {
        int js = threadIdx.x >> 4, n = threadIdx.x & 15;
        alrv[js][n] = make_float2(alpha[js * NMAX + n], rs[js * NMAX + n]);
    }
    __syncthreads();

    int wave = threadIdx.x >> 6;
    int lane = threadIdx.x & 63;
    int a = lane >> 4;        // 0..3 atom-in-wave
    int p = (lane >> 2) & 3;  // 0..3 pair slot
    int ng = lane & 3;        // 0..3 channel group
    int c0 = 4 * ng;
    int t = blockIdx.x * 16 + wave * 4 + a;
    int cnt = counts[t];
    if (cnt > SLOTS) cnt = SLOTS;
    int maxc = max(cnt, __shfl_xor(cnt, 16));
    maxc = max(maxc, __shfl_xor(maxc, 32));
    const float4* rbase = rec4 + (size_t)t * SLOTS;
    const float2* ap_base = &alrv[0][0];

    float acc[16];
#pragma unroll
    for (int i = 0; i < 16; ++i) acc[i] = 0.f;

#pragma unroll 2
    for (int kk = 0; kk < maxc; kk += 4) {
        int k = kk + p;
        bool m = (k < cnt);
        float4 R = rbase[m ? k : 0];
        int jw = __float_as_int(R.w);
        int jj = m ? (jw & 0xFFFF) : 0;
        int js = (jw >> 16) & 3;
        unsigned w0 = __float_as_uint(R.x);
        unsigned w1 = __float_as_uint(R.y);
        float x = h2f(w0 & 0xFFFFu);
        float y = h2f(w0 >> 16);
        float z = h2f(w1 & 0xFFFFu);
        float fcut = (float)(w1 >> 16) * (1.0f / 65535.0f);
        float dd = R.z;
        const float2* ap = ap_base + js * 16 + c0;
        float2 ap0 = ap[0], ap1 = ap[1], ap2 = ap[2], ap3 = ap[3];
        float4 C4 = *(const float4*)&Csn[jj * NMAX + c0];
        float d0 = dd - ap0.y, d1 = dd - ap1.y, d2 = dd - ap2.y, d3 = dd - ap3.y;
        float f0 = fcut * __expf(ap0.x * d0 * d0);
        float f1 = fcut * __expf(ap1.x * d1 * d1);
        float f2 = fcut * __expf(ap2.x * d2 * d2);
        float f3 = fcut * __expf(ap3.x * d3 * d3);
        if (!m) { f0 = 0.f; f1 = 0.f; f2 = 0.f; f3 = 0.f; }
        float fc0 = f0 * C4.x, fc1 = f1 * C4.y, fc2 = f2 * C4.z, fc3 = f3 * C4.w;
        acc[0] += fc0; acc[1] += fc1; acc[2] += fc2; acc[3] += fc3;
        acc[4] += fc0 * x; acc[5] += fc1 * x; acc[6] += fc2 * x; acc[7] += fc3 * x;
        acc[8] += fc0 * y; acc[9] += fc1 * y; acc[10] += fc2 * y; acc[11] += fc3 * y;
        acc[12] += fc0 * z; acc[13] += fc1 * z; acc[14] += fc2 * z; acc[15] += fc3 * z;
    }

#pragma unroll
    for (int i = 0; i < 16; ++i) {
        acc[i] += __shfl_xor(acc[i], 4);
        acc[i] += __shfl_xor(acc[i], 8);
    }

    float pt[16];
#pragma unroll
    for (int l = 0; l < 4; ++l) {
        const float* Wrow = orb + ((l > 0) ? 1 : 0) * (NMAX * NO);
#pragma unroll
        for (int o = 0; o < 4; ++o) {
            float s = 0.f;
#pragma unroll
            for (int c = 0; c < 4; ++c)
                s += Wrow[(c0 + c) * NO + o] * acc[l * 4 + c];
            pt[l * 4 + o] = s;
        }
    }
#pragma unroll
    for (int i = 0; i < 16; ++i) {
        pt[i] += __shfl_xor(pt[i], 1);
        pt[i] += __shfl_xor(pt[i], 2);
    }
    float r0 = 0.f, r1 = 0.f, r2 = 0.f, r3 = 0.f;
#pragma unroll
    for (int l = 0; l < 4; ++l) {
        r0 += pt[l * 4 + 0] * pt[l * 4 + 0];
        r1 += pt[l * 4 + 1] * pt[l * 4 + 1];
        r2 += pt[l * 4 + 2] * pt[l * 4 + 2];
        r3 += pt[l * 4 + 3] * pt[l * 4 + 3];
    }
    if (p == 0) {
        float v = (ng == 0) ? r0 : (ng == 1) ? r1 : (ng == 2) ? r2 : r3;
        rho_out[t * NO + ng] = v;
    }
}

// ---------------- MLP: one wave per atom, Csn += g ----------------
__global__ __launch_bounds__(256) void k_mlp(
    const float* __restrict__ rho, const int* __restrict__ symbols,
    const float* __restrict__ W1, const float* __restrict__ b1,
    const float* __restrict__ W2, const float* __restrict__ b2,
    float* __restrict__ Csn) {
    __shared__ float h_lds[4][HID];
    int wave = threadIdx.x >> 6;
    int lane = threadIdx.x & 63;
    int t = blockIdx.x * 4 + wave;
    int sym = symbols[t];
    float r0 = rho[t * 4 + 0];
    float r1 = rho[t * 4 + 1];
    float r2 = rho[t * 4 + 2];
    float r3 = rho[t * 4 + 3];
    const float* w1 = W1 + sym * NO * HID;
    const float* bb1 = b1 + sym * HID;
#pragma unroll
    for (int s = 0; s < 2; ++s) {
        int j = lane + s * 64;
        float hv = bb1[j] + r0 * w1[0 * HID + j] + r1 * w1[1 * HID + j] +
                   r2 * w1[2 * HID + j] + r3 * w1[3 * HID + j];
        hv = (hv >= 0.f) ? hv : 0.01f * hv;
        h_lds[wave][j] = hv;
    }
    __syncthreads();
    int n = lane & 15, q = lane >> 4;
    const float* w2 = W2 + sym * HID * NMAX;
    float g = 0.f;
#pragma unroll 8
    for (int k = 0; k < 32; ++k) {
        int j = q * 32 + k;
        g += h_lds[wave][j] * w2[j * NMAX + n];
    }
    g += __shfl_xor(g, 16);
    g += __shfl_xor(g, 32);
    if (lane < 16) {
        Csn[t * NMAX + n] += g + b2[sym * NMAX + n];
    }
}

extern "C" void kernel_launch(void* const* d_in, const int* in_sizes, int n_in,
                              void* d_out, int out_size, void* d_ws, size_t ws_size,
                              hipStream_t stream) {
    const float* disp    = (const float*)d_in[0];
    // d_in[1] (dist) not read — recomputed from disp in k_p2
    const float* alpha   = (const float*)d_in[2];
    const float* rs      = (const float*)d_in[3];
    const float* sp      = (const float*)d_in[4];
    const float* orb     = (const float*)d_in[5];  // (3, 2, 16, 4)
    const float* W1      = (const float*)d_in[6];
    const float* b1      = (const float*)d_in[7];
    const float* W2      = (const float*)d_in[8];
    const float* b2      = (const float*)d_in[9];
    const int* symbols   = (const int*)d_in[10];
    const int* iidx      = (const int*)d_in[11];
    const int* jidx      = (const int*)d_in[12];
    const int* jsym      = (const int*)d_in[13];

    char* base = (char*)d_ws;
    size_t off_b = 0;
    int* cnt1    = (int*)(base + off_b); off_b += (size_t)SCAN_N * 4;   // 803 KB
    int* offs    = (int*)(base + off_b); off_b += (size_t)SCAN_N * 4;   // 803 KB
    int* blksum  = (int*)(base + off_b); off_b += 1024;
    int* counts  = (int*)(base + off_b); off_b += (size_t)NTA * 4;      // 200 KB
    off_b = (off_b + 15) & ~(size_t)15;
    float4* blob = (float4*)(base + off_b); off_b += (size_t)NN * 16;   // 25.6 MB
    off_b = (off_b + 15) & ~(size_t)15;
    float4* rec4 = (float4*)(base + off_b); off_b += (size_t)NTA * SLOTS * 16;  // 64 MB
    float* Csn   = (float*)(base + off_b);  off_b += (size_t)NTA * NMAX * 4;    // 3.2 MB
    float* rho   = (float*)(base + off_b);  off_b += (size_t)NTA * NO * 4;      // 0.8 MB

    k_p1_count<<<NB1, 256, 0, stream>>>(iidx, cnt1);
    k_scan1<<<SCAN_NBLK, 1024, 0, stream>>>(cnt1, offs, blksum);
    k_scan2<<<1, 64, 0, stream>>>(blksum);
    k_scan3<<<SCAN_NBLK, 1024, 0, stream>>>(offs, blksum);
    k_p1_sort<<<NB1, 256, 0, stream>>>(disp, iidx, jidx, jsym, offs, blob);
    k_p2<<<NBKT, 512, 0, stream>>>(blob, offs, sp, symbols, rec4, counts, Csn);

    const int ORB_SLICE = 2 * NMAX * NO;  // 128 floats per loop-iteration slice
    k_density<<<NTA / 16, 256, 0, stream>>>(rec4, counts, alpha, rs, Csn,
                                            orb + 0 * ORB_SLICE, rho);
    k_mlp<<<NTA / 4, 256, 0, stream>>>(rho, symbols, W1, b1, W2, b2, Csn);
    k_density<<<NTA / 16, 256, 0, stream>>>(rec4, counts, alpha, rs, Csn,
                                            orb + 1 * ORB_SLICE, rho);
    k_mlp<<<NTA / 4, 256, 0, stream>>>(rho, symbols, W1, b1, W2, b2, Csn);
    k_density<<<NTA / 16, 256, 0, stream>>>(rec4, counts, alpha, rs, Csn,
                                            orb + 2 * ORB_SLICE, (float*)d_out);
}

// Round 26
// 165.252 us; speedup vs baseline: 1.5146x; 1.0359x over previous
//
#include <hip/hip_runtime.h>
#include <math.h>

#define NTA 50000
#define NN 1600000
#define NMAX 16
#define NO 4
#define HID 128
#define SLOTS 80        // padded per-atom capacity; counts ~Binom(1.6M,1/50e3): mean 32, sigma 5.7
#define NB1 1024        // phase-1 blocks
#define PPB 1563        // pairs per phase-1 block (1024*1563 >= NN)
#define MAXPPT 7        // ceil(PPB/256) pairs per thread
#define NBKT 196        // coarse buckets of 256 atoms (t>>8); 196*256 = 50176 >= NTA
#define SCAN_N (NBKT * NB1)   // 200704 histogram cells
#define SCAN_NBLK 196         // 200704 / 1024 exactly

static constexpr float PI_OVER_RCUT = 3.14159265358979323846f / 6.0f;

// blob record: (x, y, z, jw) ; jw bits 0-15 jidx, 16-17 jsym, 18-25 tl (= t & 255)
// rec4 record (packed by k_p2): {x:f16|y:f16, z:f16|fcut:u16fix, dd:f32, jw}

__device__ __forceinline__ unsigned f2h(float f) {
    _Float16 h = (_Float16)f;
    return (unsigned)*(unsigned short*)&h;
}
__device__ __forceinline__ float h2f(unsigned u) {
    unsigned short s = (unsigned short)u;
    _Float16 h;
    *(unsigned short*)&h = s;
    return (float)h;
}

// ---------- phase 1a: per-(bucket,block) histogram ----------
__global__ __launch_bounds__(256) void k_p1_count(const int* __restrict__ iidx,
                                                  int* __restrict__ cnt1) {
    __shared__ int h[NBKT];
    int blk = blockIdx.x;
    if (threadIdx.x < NBKT) h[threadIdx.x] = 0;
    __syncthreads();
    int pend = min(NN, (blk + 1) * PPB);
    for (int p = blk * PPB + threadIdx.x; p < pend; p += 256)
        atomicAdd(&h[iidx[p] >> 8], 1);
    __syncthreads();
    if (threadIdx.x < NBKT) cnt1[threadIdx.x * NB1 + blk] = h[threadIdx.x];
}

// ---------- exclusive scan over cnt1 (bucket-major) ----------
__global__ void k_scan1(const int* __restrict__ counts, int* __restrict__ offsets,
                        int* __restrict__ blksum) {
    __shared__ int lds[1024];
    int i = blockIdx.x * 1024 + threadIdx.x;
    int v = counts[i];  // SCAN_N is an exact multiple of 1024
    lds[threadIdx.x] = v;
    __syncthreads();
    int sum = v;
    for (int off = 1; off < 1024; off <<= 1) {
        int t = (threadIdx.x >= off) ? lds[threadIdx.x - off] : 0;
        __syncthreads();
        sum += t;
        lds[threadIdx.x] = sum;
        __syncthreads();
    }
    offsets[i] = sum - v;
    if (threadIdx.x == 1023) blksum[blockIdx.x] = sum;
}

__global__ void k_scan2(int* __restrict__ blksum) {
    if (threadIdx.x == 0) {
        int acc = 0;
        for (int b = 0; b < SCAN_NBLK; ++b) {
            int v = blksum[b];
            blksum[b] = acc;
            acc += v;
        }
    }
}

__global__ void k_scan3(int* __restrict__ offsets, const int* __restrict__ blksum) {
    int i = blockIdx.x * 1024 + threadIdx.x;
    offsets[i] += blksum[blockIdx.x];
}

// ---------- phase 1b: in-LDS counting sort, then dense burst write-out ----------
__global__ __launch_bounds__(256) void k_p1_sort(
    const float* __restrict__ disp, const int* __restrict__ iidx,
    const int* __restrict__ jidx, const int* __restrict__ jsym,
    const int* __restrict__ off, float4* __restrict__ blob) {
    __shared__ int h[256];        // hist -> exclusive scan (padded to 256)
    __shared__ int goff[NBKT];    // global segment offset for (bucket, this block)
    __shared__ float4 buf[PPB];   // bucket-sorted records
    __shared__ int gaddr[PPB];    // per-record global index
    int blk = blockIdx.x;
    int tid = threadIdx.x;
    h[tid] = 0;
    if (tid < NBKT) goff[tid] = off[tid * NB1 + blk];
    __syncthreads();
    int base = blk * PPB;
    int pend = min(NN, base + PPB);

    int myb[MAXPPT], myr[MAXPPT];
#pragma unroll
    for (int i = 0; i < MAXPPT; ++i) {
        int p = base + i * 256 + tid;
        myb[i] = -1;
        if (p < pend) {
            int b = iidx[p] >> 8;
            myb[i] = b;
            myr[i] = atomicAdd(&h[b], 1);
        }
    }
    __syncthreads();
    int cnt_t = h[tid];  // own count (pre-scan)
    // inclusive Hillis-Steele scan over 256 entries
    for (int s = 1; s < 256; s <<= 1) {
        int val = (tid >= s) ? h[tid - s] : 0;
        __syncthreads();
        h[tid] += val;
        __syncthreads();
    }
    h[tid] -= cnt_t;  // -> exclusive
    __syncthreads();

#pragma unroll
    for (int i = 0; i < MAXPPT; ++i) {
        if (myb[i] >= 0) {
            int p = base + i * 256 + tid;
            int b = myb[i];
            int lpos = h[b] + myr[i];
            int tl = iidx[p] & 255;
            int jw = jidx[p] | (jsym[p] << 16) | (tl << 18);
            buf[lpos] = make_float4(disp[3 * p + 0], disp[3 * p + 1], disp[3 * p + 2],
                                    __int_as_float(jw));
            gaddr[lpos] = goff[b] + myr[i];
        }
    }
    __syncthreads();
    int total = pend - base;
    for (int i = tid; i < total; i += 256)
        blob[gaddr[i]] = buf[i];
}

// ---------- phase 2: padded-CSR placement + dd/fcut precompute + Csn fill ----------
__global__ __launch_bounds__(512) void k_p2(
    const float4* __restrict__ blob, const int* __restrict__ off,
    const float* __restrict__ sp, const int* __restrict__ symbols,
    float4* __restrict__ rec4, int* __restrict__ counts,
    float* __restrict__ Csn) {
    __shared__ int cur[256];
    int b = blockIdx.x;
    if (threadIdx.x < 256) cur[threadIdx.x] = 0;
    __syncthreads();
    int start = off[b * NB1];
    int end = (b == NBKT - 1) ? NN : off[(b + 1) * NB1];
    for (int i = start + threadIdx.x; i < end; i += 512) {
        float4 r = blob[i];
        int jw = __float_as_int(r.w);
        int tl = ((unsigned)jw >> 18) & 255;
        float dd = sqrtf(r.x * r.x + r.y * r.y + r.z * r.z);
        float cc = __cosf(dd * PI_OVER_RCUT) + 1.0f;
        float fcut = 0.25f * cc * cc;
        unsigned fq = (unsigned)(fcut * 65535.0f + 0.5f);
        if (fq > 65535u) fq = 65535u;
        float4 o;
        o.x = __uint_as_float(f2h(r.x) | (f2h(r.y) << 16));
        o.y = __uint_as_float(f2h(r.z) | (fq << 16));
        o.z = dd;
        o.w = r.w;
        int pos = atomicAdd(&cur[tl], 1);
        if (pos < SLOTS) rec4[(size_t)(b * 256 + tl) * SLOTS + pos] = o;
    }
    __syncthreads();
    if (threadIdx.x < 256) {
        int t = b * 256 + threadIdx.x;
        if (t < NTA) counts[t] = cur[threadIdx.x];
    }
    // Csn init for this bucket (replaces the k_csn launch)
    for (int i = threadIdx.x; i < 256 * NMAX; i += 512) {
        int tl = i >> 4;
        int t = b * 256 + tl;
        if (t < NTA) Csn[(size_t)t * NMAX + (i & 15)] = sp[symbols[t] * NMAX + (i & 15)];
    }
}

// ---------------- density: FOUR atoms per wave; dd/fcut from record; alrv in LDS ----------------
// lane = a*16 + p*4 + ng.
// PASS0: Csn[jj][n] == sp[js][n] (Csn is species_params-gathered before any MLP), and js
// is packed in the record -> the dependent global Csn gather is replaced by a 256B LDS
// table read. Bit-identical arithmetic. Passes 1-2 keep the global gather.
template <bool PASS0>
__global__ __launch_bounds__(256) void k_density(
    const float4* __restrict__ rec4, const int* __restrict__ counts,
    const float* __restrict__ alpha, const float* __restrict__ rs,
    const float* __restrict__ sp, const float* __restrict__ Csn,
    const float* __restrict__ orb,  // [2][16][4] slice
    float* __restrict__ rho_out) {
    __shared__ float2 alrv[4][16];   // (alpha, rs) per species x channel
    __shared__ float4 sp_lds[16];    // sp[js][4g..4g+3] as float4, index js*4+g
    if (threadIdx.x < 64) {
        int js = threadIdx.x >> 4, n = threadIdx.x & 15;
        alrv[js][n] = make_float2(alpha[js * NMAX + n], rs[js * NMAX + n]);
    }
    if (PASS0 && threadIdx.x < 16) {
        int js = threadIdx.x >> 2, g = threadIdx.x & 3;
        sp_lds[threadIdx.x] = *(const float4*)&sp[js * NMAX + 4 * g];
    }
    __syncthreads();

    int wave = threadIdx.x >> 6;
    int lane = threadIdx.x & 63;
    int a = lane >> 4;        // 0..3 atom-in-wave
    int p = (lane >> 2) & 3;  // 0..3 pair slot
    int ng = lane & 3;        // 0..3 channel group
    int c0 = 4 * ng;
    int t = blockIdx.x * 16 + wave * 4 + a;
    int cnt = counts[t];
    if (cnt > SLOTS) cnt = SLOTS;
    int maxc = max(cnt, __shfl_xor(cnt, 16));
    maxc = max(maxc, __shfl_xor(maxc, 32));
    const float4* rbase = rec4 + (size_t)t * SLOTS;
    const float2* ap_base = &alrv[0][0];

    float acc[16];
#pragma unroll
    for (int i = 0; i < 16; ++i) acc[i] = 0.f;

#pragma unroll 2
    for (int kk = 0; kk < maxc; kk += 4) {
        int k = kk + p;
        bool m = (k < cnt);
        float4 R = rbase[m ? k : 0];
        int jw = __float_as_int(R.w);
        int js = (jw >> 16) & 3;
        unsigned w0 = __float_as_uint(R.x);
        unsigned w1 = __float_as_uint(R.y);
        float x = h2f(w0 & 0xFFFFu);
        float y = h2f(w0 >> 16);
        float z = h2f(w1 & 0xFFFFu);
        float fcut = (float)(w1 >> 16) * (1.0f / 65535.0f);
        float dd = R.z;
        const float2* ap = ap_base + js * 16 + c0;
        float2 ap0 = ap[0], ap1 = ap[1], ap2 = ap[2], ap3 = ap[3];
        float4 C4;
        if (PASS0) {
            C4 = sp_lds[js * 4 + ng];          // LDS broadcast, no global gather
        } else {
            int jj = m ? (jw & 0xFFFF) : 0;    // poison-scrubbed address
            C4 = *(const float4*)&Csn[jj * NMAX + c0];
        }
        float d0 = dd - ap0.y, d1 = dd - ap1.y, d2 = dd - ap2.y, d3 = dd - ap3.y;
        float f0 = fcut * __expf(ap0.x * d0 * d0);
        float f1 = fcut * __expf(ap1.x * d1 * d1);
        float f2 = fcut * __expf(ap2.x * d2 * d2);
        float f3 = fcut * __expf(ap3.x * d3 * d3);
        if (!m) { f0 = 0.f; f1 = 0.f; f2 = 0.f; f3 = 0.f; }
        float fc0 = f0 * C4.x, fc1 = f1 * C4.y, fc2 = f2 * C4.z, fc3 = f3 * C4.w;
        acc[0] += fc0; acc[1] += fc1; acc[2] += fc2; acc[3] += fc3;
        acc[4] += fc0 * x; acc[5] += fc1 * x; acc[6] += fc2 * x; acc[7] += fc3 * x;
        acc[8] += fc0 * y; acc[9] += fc1 * y; acc[10] += fc2 * y; acc[11] += fc3 * y;
        acc[12] += fc0 * z; acc[13] += fc1 * z; acc[14] += fc2 * z; acc[15] += fc3 * z;
    }

#pragma unroll
    for (int i = 0; i < 16; ++i) {
        acc[i] += __shfl_xor(acc[i], 4);
        acc[i] += __shfl_xor(acc[i], 8);
    }

    float pt[16];
#pragma unroll
    for (int l = 0; l < 4; ++l) {
        const float* Wrow = orb + ((l > 0) ? 1 : 0) * (NMAX * NO);
#pragma unroll
        for (int o = 0; o < 4; ++o) {
            float s = 0.f;
#pragma unroll
            for (int c = 0; c < 4; ++c)
                s += Wrow[(c0 + c) * NO + o] * acc[l * 4 + c];
            pt[l * 4 + o] = s;
        }
    }
#pragma unroll
    for (int i = 0; i < 16; ++i) {
        pt[i] += __shfl_xor(pt[i], 1);
        pt[i] += __shfl_xor(pt[i], 2);
    }
    float r0 = 0.f, r1 = 0.f, r2 = 0.f, r3 = 0.f;
#pragma unroll
    for (int l = 0; l < 4; ++l) {
        r0 += pt[l * 4 + 0] * pt[l * 4 + 0];
        r1 += pt[l * 4 + 1] * pt[l * 4 + 1];
        r2 += pt[l * 4 + 2] * pt[l * 4 + 2];
        r3 += pt[l * 4 + 3] * pt[l * 4 + 3];
    }
    if (p == 0) {
        float v = (ng == 0) ? r0 : (ng == 1) ? r1 : (ng == 2) ? r2 : r3;
        rho_out[t * NO + ng] = v;
    }
}

// ---------------- MLP: one wave per atom, Csn += g ----------------
__global__ __launch_bounds__(256) void k_mlp(
    const float* __restrict__ rho, const int* __restrict__ symbols,
    const float* __restrict__ W1, const float* __restrict__ b1,
    const float* __restrict__ W2, const float* __restrict__ b2,
    float* __restrict__ Csn) {
    __shared__ float h_lds[4][HID];
    int wave = threadIdx.x >> 6;
    int lane = threadIdx.x & 63;
    int t = blockIdx.x * 4 + wave;
    int sym = symbols[t];
    float r0 = rho[t * 4 + 0];
    float r1 = rho[t * 4 + 1];
    float r2 = rho[t * 4 + 2];
    float r3 = rho[t * 4 + 3];
    const float* w1 = W1 + sym * NO * HID;
    const float* bb1 = b1 + sym * HID;
#pragma unroll
    for (int s = 0; s < 2; ++s) {
        int j = lane + s * 64;
        float hv = bb1[j] + r0 * w1[0 * HID + j] + r1 * w1[1 * HID + j] +
                   r2 * w1[2 * HID + j] + r3 * w1[3 * HID + j];
        hv = (hv >= 0.f) ? hv : 0.01f * hv;
        h_lds[wave][j] = hv;
    }
    __syncthreads();
    int n = lane & 15, q = lane >> 4;
    const float* w2 = W2 + sym * HID * NMAX;
    float g = 0.f;
#pragma unroll 8
    for (int k = 0; k < 32; ++k) {
        int j = q * 32 + k;
        g += h_lds[wave][j] * w2[j * NMAX + n];
    }
    g += __shfl_xor(g, 16);
    g += __shfl_xor(g, 32);
    if (lane < 16) {
        Csn[t * NMAX + n] += g + b2[sym * NMAX + n];
    }
}

extern "C" void kernel_launch(void* const* d_in, const int* in_sizes, int n_in,
                              void* d_out, int out_size, void* d_ws, size_t ws_size,
                              hipStream_t stream) {
    const float* disp    = (const float*)d_in[0];
    // d_in[1] (dist) not read — recomputed from disp in k_p2
    const float* alpha   = (const float*)d_in[2];
    const float* rs      = (const float*)d_in[3];
    const float* sp      = (const float*)d_in[4];
    const float* orb     = (const float*)d_in[5];  // (3, 2, 16, 4)
    const float* W1      = (const float*)d_in[6];
    const float* b1      = (const float*)d_in[7];
    const float* W2      = (const float*)d_in[8];
    const float* b2      = (const float*)d_in[9];
    const int* symbols   = (const int*)d_in[10];
    const int* iidx      = (const int*)d_in[11];
    const int* jidx      = (const int*)d_in[12];
    const int* jsym      = (const int*)d_in[13];

    char* base = (char*)d_ws;
    size_t off_b = 0;
    int* cnt1    = (int*)(base + off_b); off_b += (size_t)SCAN_N * 4;   // 803 KB
    int* offs    = (int*)(base + off_b); off_b += (size_t)SCAN_N * 4;   // 803 KB
    int* blksum  = (int*)(base + off_b); off_b += 1024;
    int* counts  = (int*)(base + off_b); off_b += (size_t)NTA * 4;      // 200 KB
    off_b = (off_b + 15) & ~(size_t)15;
    float4* blob = (float4*)(base + off_b); off_b += (size_t)NN * 16;   // 25.6 MB
    off_b = (off_b + 15) & ~(size_t)15;
    float4* rec4 = (float4*)(base + off_b); off_b += (size_t)NTA * SLOTS * 16;  // 64 MB
    float* Csn   = (float*)(base + off_b);  off_b += (size_t)NTA * NMAX * 4;    // 3.2 MB
    float* rho   = (float*)(base + off_b);  off_b += (size_t)NTA * NO * 4;      // 0.8 MB

    k_p1_count<<<NB1, 256, 0, stream>>>(iidx, cnt1);
    k_scan1<<<SCAN_NBLK, 1024, 0, stream>>>(cnt1, offs, blksum);
    k_scan2<<<1, 64, 0, stream>>>(blksum);
    k_scan3<<<SCAN_NBLK, 1024, 0, stream>>>(offs, blksum);
    k_p1_sort<<<NB1, 256, 0, stream>>>(disp, iidx, jidx, jsym, offs, blob);
    k_p2<<<NBKT, 512, 0, stream>>>(blob, offs, sp, symbols, rec4, counts, Csn);

    const int ORB_SLICE = 2 * NMAX * NO;  // 128 floats per loop-iteration slice
    k_density<true><<<NTA / 16, 256, 0, stream>>>(rec4, counts, alpha, rs, sp, Csn,
                                                  orb + 0 * ORB_SLICE, rho);
    k_mlp<<<NTA / 4, 256, 0, stream>>>(rho, symbols, W1, b1, W2, b2, Csn);
    k_density<false><<<NTA / 16, 256, 0, stream>>>(rec4, counts, alpha, rs, sp, Csn,
                                                   orb + 1 * ORB_SLICE, rho);
    k_mlp<<<NTA / 4, 256, 0, stream>>>(rho, symbols, W1, b1, W2, b2, Csn);
    k_density<false><<<NTA / 16, 256, 0, stream>>>(rec4, counts, alpha, rs, sp, Csn,
                                                   orb + 2 * ORB_SLICE, (float*)d_out);
}